// Round 6
// baseline (731.304 us; speedup 1.0000x reference)
//
#include <hip/hip_runtime.h>

// CRF forward v6: ONE WAVE per sequence, register-only alpha exchange
// (v4b network, validated end-to-end) with the three diagnosed v4b defects
// fixed:
//  1. gold score computed BEFORE E init + sched_barrier(0) phase fences:
//     v4b's post-E gold loop hoisted ~64 loads over the 128 live E regs,
//     peak >256 -> compiler homed E in AGPRs -> +~700 cyc/step of
//     dependent v_accvgpr_read traffic. Keeping peak <256 keeps E in
//     arch VGPRs (diagnostic: VGPR_Count should rise 144 -> ~190).
//  2. the two ds_swizzle (xor16) ops are issued FIRST in the step; their
//     DS-pipe latency hides under the ~128 issue-cycles of the g0/g1
//     quadrant dots that do not depend on them.
//  3. gather expansion in 8-slot chunks (A: ror 1,2,4; B: ror8 of A),
//     consumed immediately -> gather working set <= 16 regs.
// Exchange network per step (all validated in v4b, absmax 0.5):
//   v_permlane32_swap (+-32) -> 2x ds_swizzle 0x401F (xor16) -> row_ror
//   doubling; E is loaded PERMUTED VIA A PROBE (lane id pushed through the
//   identical network), so pairing is correct by construction.
// Numerics: v1's validated stale power-of-2 normalizer (P = Em - P + 6,
// exact integer Kacc side chain). No LDS, no barriers in the loop.

typedef _Float16 half_t;
typedef _Float16 h2 __attribute__((ext_vector_type(2)));

#define TB  1024
#define NUM 126
#define LBL 128

__device__ __forceinline__ float dot2f(h2 a, h2 b, float c) {
  return __builtin_amdgcn_fdot2(a, b, c, false);
}

__device__ __forceinline__ h2 bits_h2(int x) {
  union { int i; h2 h; } u; u.i = x; return u.h;
}
__device__ __forceinline__ int h2_bits(h2 h) {
  union { int i; h2 h; } u; u.h = h; return u.i;
}

template <int N>
__device__ __forceinline__ int ror(int x) {
  return __builtin_amdgcn_update_dpp(x, x, 0x120 | N, 0xF, 0xF, false);
}

template <int CTRL>
__device__ __forceinline__ float dpp_fmax(float x) {
  int xi = __float_as_int(x);
  int yi = __builtin_amdgcn_update_dpp(xi, xi, CTRL, 0xF, 0xF, false);
  return fmaxf(x, __int_as_float(yi));
}

// max over all 64 lanes -> uniform via readlane(63)  (validated v1)
__device__ __forceinline__ float wave_max64(float x) {
  x = dpp_fmax<0x111>(x);  // row_shr:1
  x = dpp_fmax<0x112>(x);  // row_shr:2
  x = dpp_fmax<0x114>(x);  // row_shr:4
  x = dpp_fmax<0x118>(x);  // row_shr:8
  x = dpp_fmax<0x142>(x);  // row_bcast:15
  x = dpp_fmax<0x143>(x);  // row_bcast:31
  return __int_as_float(__builtin_amdgcn_readlane(__float_as_int(x), 63));
}

// slots 0..7 of a base: ror 1,2,4 doubling (depth 3)
__device__ __forceinline__ void expand8A(int base, int rr[8]) {
  rr[0] = base;
  rr[1] = ror<1>(rr[0]);
  rr[2] = ror<2>(rr[0]);  rr[3] = ror<2>(rr[1]);
  rr[4] = ror<4>(rr[0]);  rr[5] = ror<4>(rr[1]);
  rr[6] = ror<4>(rr[2]);  rr[7] = ror<4>(rr[3]);
}
// slots 8..15: ror8 of slots 0..7
__device__ __forceinline__ void expand8B(const int rrA[8], int rr[8]) {
  #pragma unroll
  for (int i = 0; i < 8; ++i) rr[i] = ror<8>(rrA[i]);
}

__global__ __launch_bounds__(64, 1)
void crf_fwd(const float* __restrict__ logits, const int* __restrict__ labels,
             const int* __restrict__ lens, const float* __restrict__ trans,
             float* __restrict__ out)
{
  const int b  = blockIdx.x;
  const int l  = threadIdx.x;          // lane 0..63
  const int r0 = 2 * l;                // even state owned by this lane
  const int r1 = 2 * l + 1;            // odd state
  const float rm0 = (r0 < NUM) ? 1.0f : 0.0f;   // states 126,127 dead
  const float rm1 = (r1 < NUM) ? 1.0f : 0.0f;
  const int cl  = (r1 < NUM) ? r0 : (NUM - 2);  // even, float2-safe col base
  const int len = lens[b];

  const float* lgbase = logits + (size_t)b * TB * NUM;
  const int*   lab    = labels + (size_t)b * TB;

  // ==== phase 1: gold score (BEFORE E init -- keeps peak pressure low)
  float gacc = 0.f;
  #pragma unroll
  for (int kk = 0; kk < 16; ++kk) {
    int t = l + 64 * kk;
    if (t < len) {
      int lt = lab[t];
      int lp = (t == 0) ? (LBL - 2) : lab[t - 1];   // start state = 126
      gacc += lgbase[(size_t)t * NUM + lt] + trans[lt * LBL + lp];
    }
  }
  if (l == 0) gacc += trans[(LBL - 1) * LBL + lab[len - 1]];  // -> end
  #pragma unroll
  for (int o = 1; o < 64; o <<= 1) gacc += __shfl_xor(gacc, o);
  const float gold = gacc;

  __builtin_amdgcn_sched_barrier(0);   // fence: gold loads stay in phase 1

  // ==== phase 2: E rows (f16), permuted via the probe. Slot 16v+k pairs
  // with the alpha dword of source lane s -> states (2s, 2s+1).
  h2 E0[64], E1[64];
  {
    int g0p = l, g1p = l;
    asm("v_permlane32_swap_b32 %0, %1" : "+v"(g0p), "+v"(g1p));
    int s0p = __builtin_amdgcn_ds_swizzle(g0p, 0x401F);
    int s1p = __builtin_amdgcn_ds_swizzle(g1p, 0x401F);
    int bases[4] = {g0p, g1p, s0p, s1p};
    const float* t0 = trans + r0 * LBL;
    const float* t1 = trans + r1 * LBL;
    #pragma unroll
    for (int v = 0; v < 4; ++v) {
      int rrA[8], rrB[8];
      expand8A(bases[v], rrA);
      expand8B(rrA, rrB);
      #pragma unroll
      for (int k = 0; k < 8; ++k) {
        int sa = rrA[k], sb = rrB[k];
        h2 e;
        e[0] = (half_t)__expf(t0[2 * sa]);  e[1] = (half_t)__expf(t0[2 * sa + 1]);
        E0[16 * v + k] = e;
        e[0] = (half_t)__expf(t1[2 * sa]);  e[1] = (half_t)__expf(t1[2 * sa + 1]);
        E1[16 * v + k] = e;
        e[0] = (half_t)__expf(t0[2 * sb]);  e[1] = (half_t)__expf(t0[2 * sb + 1]);
        E0[16 * v + 8 + k] = e;
        e[0] = (half_t)__expf(t1[2 * sb]);  e[1] = (half_t)__expf(t1[2 * sb + 1]);
        E1[16 * v + 8 + k] = e;
      }
      __builtin_amdgcn_sched_barrier(0);  // cap init-phase pressure
    }
  }

  // ==== phase 3: recurrence state + prefetch
  h2 a_init;
  a_init[0] = (half_t)((r0 == LBL - 2) ? 1.0f : 0.0f);  // lane 63: (a126,a127)
  a_init[1] = (half_t)0.0f;
  int   cur = h2_bits(a_init);
  int   P = 6, Kacc = 0, Kout = 0;
  float w0_out = 1.f, w1_out = 1.f;

  float2 plg[4];
  #pragma unroll
  for (int d = 0; d < 4; ++d)
    plg[d] = *(const float2*)(lgbase + (size_t)d * NUM + cl);

  auto step = [&](float2 Qv) __attribute__((always_inline)) {
    // bases; swizzles FIRST (latency hides under g0/g1-quadrant dots)
    int g0 = cur, g1 = cur;
    asm("v_permlane32_swap_b32 %0, %1" : "+v"(g0), "+v"(g1));
    int s0 = __builtin_amdgcn_ds_swizzle(g0, 0x401F);
    int s1 = __builtin_amdgcn_ds_swizzle(g1, 0x401F);
    float eL0 = __expf(Qv.x) * rm0;
    float eL1 = __expf(Qv.y) * rm1;
    float a0 = 0.f, a1 = 0.f, a2 = 0.f, a3 = 0.f;
    float b0 = 0.f, b1 = 0.f, b2 = 0.f, b3 = 0.f;
    {
      int rrA[8], rrB[8];
      expand8A(g0, rrA);
      expand8B(rrA, rrB);
      #pragma unroll
      for (int k = 0; k < 8; ++k) {
        h2 xa = bits_h2(rrA[k]), xb = bits_h2(rrB[k]);
        a0 = dot2f(xa, E0[k],     a0);  b0 = dot2f(xa, E1[k],     b0);
        a0 = dot2f(xb, E0[8 + k], a0);  b0 = dot2f(xb, E1[8 + k], b0);
      }
    }
    {
      int rrA[8], rrB[8];
      expand8A(g1, rrA);
      expand8B(rrA, rrB);
      #pragma unroll
      for (int k = 0; k < 8; ++k) {
        h2 xa = bits_h2(rrA[k]), xb = bits_h2(rrB[k]);
        a1 = dot2f(xa, E0[16 + k], a1);  b1 = dot2f(xa, E1[16 + k], b1);
        a1 = dot2f(xb, E0[24 + k], a1);  b1 = dot2f(xb, E1[24 + k], b1);
      }
    }
    {
      int rrA[8], rrB[8];
      expand8A(s0, rrA);
      expand8B(rrA, rrB);
      #pragma unroll
      for (int k = 0; k < 8; ++k) {
        h2 xa = bits_h2(rrA[k]), xb = bits_h2(rrB[k]);
        a2 = dot2f(xa, E0[32 + k], a2);  b2 = dot2f(xa, E1[32 + k], b2);
        a2 = dot2f(xb, E0[40 + k], a2);  b2 = dot2f(xb, E1[40 + k], b2);
      }
    }
    {
      int rrA[8], rrB[8];
      expand8A(s1, rrA);
      expand8B(rrA, rrB);
      #pragma unroll
      for (int k = 0; k < 8; ++k) {
        h2 xa = bits_h2(rrA[k]), xb = bits_h2(rrB[k]);
        a3 = dot2f(xa, E0[48 + k], a3);  b3 = dot2f(xa, E1[48 + k], b3);
        a3 = dot2f(xb, E0[56 + k], a3);  b3 = dot2f(xb, E1[56 + k], b3);
      }
    }
    float w0 = ((a0 + a1) + (a2 + a3)) * eL0;
    float w1 = ((b0 + b1) + (b2 + b3)) * eL1;
    float sc = __int_as_float((127 - P) << 23);   // 2^-P, SGPR, EXACT
    h2 pk;
    pk[0] = (half_t)(w0 * sc);
    pk[1] = (half_t)(w1 * sc);
    cur = h2_bits(pk);                 // next step reads the REGISTER
    Kout = Kacc;  Kacc += P;           // SALU side chain
    float m  = wave_max64(fmaxf(w0, w1));   // off-chain: feeds next step
    int   Em = ((__float_as_int(m) >> 23) & 0xFF) - 127;
    P = Em - P + 6;                    // feedback: bounded, no random walk
    w0_out = w0;  w1_out = w1;
  };

  int t = 0;
  for (; t + 4 <= len; t += 4) {
    int q0 = t + 4, q1 = t + 5, q2 = t + 6, q3 = t + 7;
    q0 = (q0 < TB) ? q0 : (TB - 1);  q1 = (q1 < TB) ? q1 : (TB - 1);
    q2 = (q2 < TB) ? q2 : (TB - 1);  q3 = (q3 < TB) ? q3 : (TB - 1);
    step(plg[0]);
    plg[0] = *(const float2*)(lgbase + (size_t)q0 * NUM + cl);
    step(plg[1]);
    plg[1] = *(const float2*)(lgbase + (size_t)q1 * NUM + cl);
    step(plg[2]);
    plg[2] = *(const float2*)(lgbase + (size_t)q2 * NUM + cl);
    step(plg[3]);
    plg[3] = *(const float2*)(lgbase + (size_t)q3 * NUM + cl);
  }
  const int rem = len - t;
  if (rem > 0) step(plg[0]);
  if (rem > 1) step(plg[1]);
  if (rem > 2) step(plg[2]);

  // ---- alpha_len[j] = Kout*ln2 + log(w_len[j]); norm = logsumexp(+trans_end)
  const float LN2 = 0.6931471805599453f;
  float K = (float)Kout * LN2;
  float v0 = K + __logf(w0_out) + trans[(LBL - 1) * LBL + r0];
  float v1 = K + __logf(w1_out) + trans[(LBL - 1) * LBL + r1];
  float M = wave_max64(fmaxf(v0, v1));
  float p = __expf(v0 - M) + __expf(v1 - M);    // dead states: w=0 -> 0
  #pragma unroll
  for (int o = 1; o < 64; o <<= 1) p += __shfl_xor(p, o);
  if (l == 0) out[b] = gold - (M + __logf(p));
}

extern "C" void kernel_launch(void* const* d_in, const int* in_sizes, int n_in,
                              void* d_out, int out_size, void* d_ws, size_t ws_size,
                              hipStream_t stream) {
  const float* logits = (const float*)d_in[0];
  const int*   labels = (const int*)d_in[1];
  const int*   lens   = (const int*)d_in[2];
  const float* trans  = (const float*)d_in[3];
  float* out = (float*)d_out;
  (void)in_sizes; (void)n_in; (void)out_size; (void)d_ws; (void)ws_size;
  crf_fwd<<<256, 64, 0, stream>>>(logits, labels, lens, trans, out);
}